// Round 7
// baseline (1084.587 us; speedup 1.0000x reference)
//
#include <hip/hip_runtime.h>
#include <math.h>

#define K 32
#define G 8
#define SIGMA_V 1.0f
#define RF __builtin_amdgcn_readfirstlane
#define RPB 512            // rows per stats block (4 waves x 128)
#define RPW 128            // rows per wave

// ws layout (4-byte units)
#define RAW_OFF   0        // float[G*K*K] = 8192
#define MUSUM_OFF 8192     // float[G*K]   = 256
#define CNT_OFF   8448     // float[G]
#define ICNT_OFF  8456     // int[G]
#define CUR_OFF   8464     // int[G]
#define DESC_OFF  8480     // int[3 * nblk] (nblk <= B/RPB + G = 2056 -> 6168 ints, fits < 7904)
#define IDX_OFF   16384    // int[B + 16*G]
#define HDR_INTS  16384

// ---------------- histogram ----------------
__global__ __launch_bounds__(256, 8) void gmm_hist(const int* __restrict__ lab,
                                                   int* __restrict__ wsI, int B) {
  __shared__ int h[G];
  if (threadIdx.x < G) h[threadIdx.x] = 0;
  __syncthreads();
  int c[G];
  #pragma unroll
  for (int g = 0; g < G; ++g) c[g] = 0;
  const int nt = gridDim.x * blockDim.x;
  const int4* lab4 = reinterpret_cast<const int4*>(lab);
  for (int i = blockIdx.x * blockDim.x + threadIdx.x; i < B / 4; i += nt) {
    const int4 v = lab4[i];
    #pragma unroll
    for (int g = 0; g < G; ++g)
      c[g] += (v.x == g) + (v.y == g) + (v.z == g) + (v.w == g);
  }
  const int lane = threadIdx.x & 63;
  #pragma unroll
  for (int g = 0; g < G; ++g) {
    int t = c[g];
    #pragma unroll
    for (int off = 32; off >= 1; off >>= 1) t += __shfl_xor(t, off);
    if (lane == 0) atomicAdd(&h[g], t);
  }
  __syncthreads();
  if (threadIdx.x < G) atomicAdd(&wsI[ICNT_OFF + threadIdx.x], h[threadIdx.x]);
}

// ---------------- prep: 16-padded offsets, cursors, per-block descriptors ----------------
__global__ void gmm_prep(float* __restrict__ ws, int* __restrict__ wsI, int B, int nblk) {
  __shared__ int off[G], bb[G + 1], scnt[G];
  const int tid = threadIdx.x;
  if (tid == 0) {
    int o = 0, b = 0;
    for (int g = 0; g < G; ++g) {
      const int c = wsI[ICNT_OFF + g];
      scnt[g] = c; off[g] = o; bb[g] = b;
      ws[CNT_OFF + g] = (float)c;
      wsI[CUR_OFF + g] = o;
      o = (o + c + 15) & ~15;          // 16-int padding: block starts stay int4-aligned
      b += (c + RPB - 1) / RPB;
    }
    bb[G] = b;
  }
  __syncthreads();
  for (int t = tid; t < nblk; t += blockDim.x) {
    int st = 0, cn = 0, gg = 0;
    #pragma unroll
    for (int g = 0; g < G; ++g) {
      if (t >= bb[g] && t < bb[g + 1]) {
        const int k = t - bb[g];
        st = off[g] + k * RPB;
        const int rem = scnt[g] - k * RPB;
        cn = rem < RPB ? rem : RPB;
        gg = g;
      }
    }
    wsI[DESC_OFF + 3 * t]     = st;
    wsI[DESC_OFF + 3 * t + 1] = cn;
    wsI[DESC_OFF + 3 * t + 2] = gg;
  }
}

// ---------------- scatter: build group-sorted row-index array ----------------
__global__ __launch_bounds__(256, 8) void gmm_scatter(const int* __restrict__ lab,
                                                      int* __restrict__ wsI, int B) {
  __shared__ int lcnt[G], lbase[G], lpos[G];
  const int tid = threadIdx.x;
  const int base = blockIdx.x * 1024;
  if (tid < G) { lcnt[tid] = 0; lpos[tid] = 0; }
  __syncthreads();
  const int4 v = *reinterpret_cast<const int4*>(lab + base + tid * 4);
  atomicAdd(&lcnt[v.x], 1); atomicAdd(&lcnt[v.y], 1);
  atomicAdd(&lcnt[v.z], 1); atomicAdd(&lcnt[v.w], 1);
  __syncthreads();
  if (tid < G) lbase[tid] = atomicAdd(&wsI[CUR_OFF + tid], lcnt[tid]);
  __syncthreads();
  int p;
  p = atomicAdd(&lpos[v.x], 1); wsI[IDX_OFF + lbase[v.x] + p] = base + tid * 4;
  p = atomicAdd(&lpos[v.y], 1); wsI[IDX_OFF + lbase[v.y] + p] = base + tid * 4 + 1;
  p = atomicAdd(&lpos[v.z], 1); wsI[IDX_OFF + lbase[v.z] + p] = base + tid * 4 + 2;
  p = atomicAdd(&lpos[v.w], 1); wsI[IDX_OFF + lbase[v.w] + p] = base + tid * 4 + 3;
}

// ---------------- stats: 1 wave = 128 rows of ONE group; 4x4 tile/lane ----------------
#define OUTER(a, b) { \
  acc[0]=fmaf(a.x,b.x,acc[0]);   acc[1]=fmaf(a.x,b.y,acc[1]);   acc[2]=fmaf(a.x,b.z,acc[2]);   acc[3]=fmaf(a.x,b.w,acc[3]); \
  acc[4]=fmaf(a.y,b.x,acc[4]);   acc[5]=fmaf(a.y,b.y,acc[5]);   acc[6]=fmaf(a.y,b.z,acc[6]);   acc[7]=fmaf(a.y,b.w,acc[7]); \
  acc[8]=fmaf(a.z,b.x,acc[8]);   acc[9]=fmaf(a.z,b.y,acc[9]);   acc[10]=fmaf(a.z,b.z,acc[10]); acc[11]=fmaf(a.z,b.w,acc[11]); \
  acc[12]=fmaf(a.w,b.x,acc[12]); acc[13]=fmaf(a.w,b.y,acc[13]); acc[14]=fmaf(a.w,b.z,acc[14]); acc[15]=fmaf(a.w,b.w,acc[15]); \
  if (i8 == 0) { ms[0]+=b.x; ms[1]+=b.y; ms[2]+=b.z; ms[3]+=b.w; } }

__global__ __launch_bounds__(256, 8) void gmm_stats2(const float* __restrict__ mu,
                                                     const int* __restrict__ wsI,
                                                     float* __restrict__ ws) {
  const int bd  = blockIdx.x * 3;
  const int s   = RF(wsI[DESC_OFF + bd]);
  const int cnt = RF(wsI[DESC_OFF + bd + 1]);
  const int g   = RF(wsI[DESC_OFF + bd + 2]);
  if (cnt <= 0) return;                      // uniform, before any barrier

  const int tid = threadIdx.x, wave = tid >> 6, lane = tid & 63;
  const int i8 = lane >> 3, j8 = lane & 7;   // lane = 8x8 grid; thread tile = rows 4*i8.., cols 4*j8..
  float acc[16], ms[4];
  #pragma unroll
  for (int e = 0; e < 16; ++e) acc[e] = 0.f;
  ms[0] = ms[1] = ms[2] = ms[3] = 0.f;

  int wcnt = cnt - wave * RPW;
  wcnt = wcnt < 0 ? 0 : (wcnt > RPW ? RPW : wcnt);
  const int* idxp = wsI + IDX_OFF + s + wave * RPW;   // s 16-aligned -> int4-aligned

  if (wcnt > 0) {
    const int n16 = wcnt & ~15;
    if (n16) {
      int4 iv[4];
      #pragma unroll
      for (int k = 0; k < 4; ++k) iv[k] = *reinterpret_cast<const int4*>(idxp + 4 * k);
      #pragma unroll 1
      for (int c0 = 0; c0 < n16; c0 += 16) {
        int sr[16];
        #pragma unroll
        for (int k = 0; k < 4; ++k) {        // ONE vmcnt drain per 16 rows
          sr[4*k+0] = RF(iv[k].x); sr[4*k+1] = RF(iv[k].y);
          sr[4*k+2] = RF(iv[k].z); sr[4*k+3] = RF(iv[k].w);
        }
        if (c0 + 16 < n16) {                 // issue next idx AFTER rf (never drained)
          #pragma unroll
          for (int k = 0; k < 4; ++k)
            iv[k] = *reinterpret_cast<const int4*>(idxp + c0 + 16 + 4 * k);
        }
        float4 A[4], Bv[4], nA[4], nB[4];
        #pragma unroll
        for (int k = 0; k < 4; ++k) {
          const float* rp = mu + (size_t)(unsigned)sr[k] * K;   // scalar base -> saddr load
          A[k]  = *reinterpret_cast<const float4*>(rp + i8 * 4);
          Bv[k] = *reinterpret_cast<const float4*>(rp + j8 * 4);
        }
        #pragma unroll
        for (int grp = 0; grp < 4; ++grp) {
          if (grp < 3) {
            #pragma unroll
            for (int k = 0; k < 4; ++k) {
              const float* rp = mu + (size_t)(unsigned)sr[(grp + 1) * 4 + k] * K;
              nA[k] = *reinterpret_cast<const float4*>(rp + i8 * 4);
              nB[k] = *reinterpret_cast<const float4*>(rp + j8 * 4);
            }
          }
          #pragma unroll
          for (int k = 0; k < 4; ++k) {
            const float4 a = A[k], b = Bv[k];
            OUTER(a, b);
          }
          #pragma unroll
          for (int k = 0; k < 4; ++k) { A[k] = nA[k]; Bv[k] = nB[k]; }
        }
      }
    }
    for (int q = n16; q < wcnt; ++q) {       // tail <= 15 rows
      const int r = RF(idxp[q]);
      const float* rp = mu + (size_t)(unsigned)r * K;
      const float4 a = *reinterpret_cast<const float4*>(rp + i8 * 4);
      const float4 b = *reinterpret_cast<const float4*>(rp + j8 * 4);
      OUTER(a, b);
    }
  }

  // cross-wave LDS reduce, element-major layout (consecutive lanes -> consecutive banks)
  __shared__ float red[4][1056];
  #pragma unroll
  for (int e = 0; e < 16; ++e) red[wave][e * 64 + lane] = acc[e];
  if (i8 == 0) {
    #pragma unroll
    for (int e = 0; e < 4; ++e) red[wave][1024 + j8 * 4 + e] = ms[e];
  }
  __syncthreads();
  for (int t = tid; t < 1056; t += 256) {
    const float sm = red[0][t] + red[1][t] + red[2][t] + red[3][t];
    if (t < 1024) {
      const int e = t >> 6, ln = t & 63;
      const int row = 4 * (ln >> 3) + (e >> 2), col = 4 * (ln & 7) + (e & 3);
      atomicAdd(ws + RAW_OFF + g * K * K + row * K + col, sm);
    } else {
      atomicAdd(ws + MUSUM_OFF + g * K + (t - 1024), sm);
    }
  }
}

// ---------------- fallback stats (round-2 style) if ws too small ----------------
#define ACC_CASE(gc_, Av, Bv_) do{ \
  facc[gc_][0]=fmaf(Av.x,Bv_.x,facc[gc_][0]); facc[gc_][1]=fmaf(Av.x,Bv_.y,facc[gc_][1]); \
  facc[gc_][2]=fmaf(Av.y,Bv_.x,facc[gc_][2]); facc[gc_][3]=fmaf(Av.y,Bv_.y,facc[gc_][3]); \
  if (a_blk==0){ msum[gc_][0]+=Bv_.x; msum[gc_][1]+=Bv_.y; } }while(0)
#define PROC(gv, Av, Bv_) switch(gv){ \
  case 0: ACC_CASE(0,Av,Bv_); break; case 1: ACC_CASE(1,Av,Bv_); break; \
  case 2: ACC_CASE(2,Av,Bv_); break; case 3: ACC_CASE(3,Av,Bv_); break; \
  case 4: ACC_CASE(4,Av,Bv_); break; case 5: ACC_CASE(5,Av,Bv_); break; \
  case 6: ACC_CASE(6,Av,Bv_); break; default: ACC_CASE(7,Av,Bv_); break; }

__global__ __launch_bounds__(256, 4) void gmm_stats_fb(const float* __restrict__ mu,
                                                       const int* __restrict__ lab,
                                                       float* __restrict__ ws, int B) {
  const int tid = threadIdx.x;
  const int a_blk = tid >> 4, b_blk = tid & 15;
  const int rpb = B / 1024;
  const long rbase = (long)blockIdx.x * rpb;
  float facc[G][4]; float msum[G][2];
  #pragma unroll
  for (int g = 0; g < G; ++g) { facc[g][0]=facc[g][1]=facc[g][2]=facc[g][3]=0.f; msum[g][0]=msum[g][1]=0.f; }
  const float2* __restrict__ mu2 = reinterpret_cast<const float2*>(mu);
  for (int q = 0; q < rpb; ++q) {
    const long r = rbase + q;
    const float2 Av = mu2[r * 16 + a_blk];
    const float2 Bv_ = mu2[r * 16 + b_blk];
    const int g0 = RF(lab[r]);
    PROC(g0, Av, Bv_);
  }
  const int arow = a_blk * 2, bcol = b_blk * 2;
  #pragma unroll
  for (int g = 0; g < G; ++g) {
    float* base = &ws[RAW_OFF + g * K * K];
    atomicAdd(base + (arow)*K + bcol, facc[g][0]);
    atomicAdd(base + (arow)*K + bcol + 1, facc[g][1]);
    atomicAdd(base + (arow+1)*K + bcol, facc[g][2]);
    atomicAdd(base + (arow+1)*K + bcol + 1, facc[g][3]);
  }
  if (a_blk == 0)
    #pragma unroll
    for (int g = 0; g < G; ++g) {
      atomicAdd(&ws[MUSUM_OFF + g*K + bcol], msum[g][0]);
      atomicAdd(&ws[MUSUM_OFF + g*K + bcol + 1], msum[g][1]);
    }
}

// ---------------- finalize (fp64, validated rounds 2/5/6) ----------------
__global__ __launch_bounds__(512, 1) void gmm_finalize(const float* __restrict__ ws,
                                                       float* __restrict__ out, int B) {
  __shared__ double sig[G][K][K];
  __shared__ double inv[G][K][K];
  __shared__ double mg[G][K];
  __shared__ double ldet[G];
  __shared__ double cshared[G];
  __shared__ double pairsum[G];
  const int tid = threadIdx.x;
  const int w = tid >> 6;
  const int lane = tid & 63;

  if (tid < G) cshared[tid] = (double)ws[CNT_OFF + tid];
  __syncthreads();
  const double cinv = 1.0 / cshared[w];
  if (lane < K) mg[w][lane] = (double)ws[MUSUM_OFF + w * K + lane] * cinv;
  __syncthreads();
  for (int e = lane; e < K * K; e += 64) {
    const int a = e >> 5, b = e & 31;
    double s = (double)ws[RAW_OFF + w * K * K + e] * cinv - mg[w][a] * mg[w][b];
    if (a == b) s += (double)SIGMA_V;
    sig[w][a][b] = s;
  }
  __syncthreads();

  const int c = lane & 31;
  double col[K];
  #pragma unroll
  for (int i2 = 0; i2 < K; ++i2) {
    double sv = sig[w][i2][c];
    col[i2] = (lane < K) ? sv : ((i2 == c) ? 1.0 : 0.0);
  }
  double ld = 0.0;
  #pragma unroll
  for (int j2 = 0; j2 < K; ++j2) {
    double rowj = col[j2];
    double p = __shfl(rowj, j2);
    double pinv = 1.0 / p;
    ld += log(p);
    double scaled = rowj * pinv;
    #pragma unroll
    for (int i2 = 0; i2 < K; ++i2) {
      if (i2 == j2) continue;
      double bij = __shfl(col[i2], j2);
      col[i2] = fma(-bij, scaled, col[i2]);
    }
    col[j2] = scaled;
  }
  if (lane >= K) {
    #pragma unroll
    for (int i2 = 0; i2 < K; ++i2) inv[w][i2][lane - K] = col[i2];
  }
  if (lane == 0) ldet[w] = ld;
  __syncthreads();

  double accp = 0.0;
  for (int jj = 0; jj < G; ++jj) {
    const bool ok = (w < G - 1) && (jj >= 1) && (w != jj);
    if (ok) {
      double t = 0.0;
      for (int e = lane; e < K * K; e += 64) {
        const int a = e >> 5, b = e & 31;
        const double da = mg[jj][a] - mg[w][a];
        const double db = mg[jj][b] - mg[w][b];
        t += inv[jj][a][b] * (sig[w][a][b] + da * db);
      }
      #pragma unroll
      for (int off = 32; off >= 1; off >>= 1) t += __shfl_xor(t, off);
      if (lane == 0) accp += 0.5 * (t - (double)K + ldet[jj] - ldet[w]) * cshared[w] * cshared[jj];
    }
  }
  if (lane == 0) pairsum[w] = accp;
  __syncthreads();
  if (tid == 0) {
    double tot = 0.0;
    #pragma unroll
    for (int q = 0; q < G; ++q) tot += pairsum[q];
    const double Bf = (double)B;
    out[0] = (float)(tot / (Bf * Bf));
  }
}

extern "C" void kernel_launch(void* const* d_in, const int* in_sizes, int n_in,
                              void* d_out, int out_size, void* d_ws, size_t ws_size,
                              hipStream_t stream) {
  const float* mu = (const float*)d_in[0];
  const int* lab = (const int*)d_in[1];
  float* ws = (float*)d_ws;
  int* wsI = (int*)d_ws;
  float* out = (float*)d_out;
  const int B = in_sizes[1];

  hipMemsetAsync(d_ws, 0, (size_t)DESC_OFF * 4, stream);
  hipLaunchKernelGGL(gmm_hist, dim3(256), dim3(256), 0, stream, lab, wsI, B);

  const size_t need = (size_t)(HDR_INTS + B + 16 * G + 32) * 4;
  if (ws_size >= need) {
    const int nblk = (B + RPB - 1) / RPB + G;
    hipLaunchKernelGGL(gmm_prep, dim3(1), dim3(256), 0, stream, ws, wsI, B, nblk);
    hipLaunchKernelGGL(gmm_scatter, dim3(B / 1024), dim3(256), 0, stream, lab, wsI, B);
    hipLaunchKernelGGL(gmm_stats2, dim3(nblk), dim3(256), 0, stream, mu, wsI, ws);
  } else {
    hipLaunchKernelGGL(gmm_prep, dim3(1), dim3(256), 0, stream, ws, wsI, B, 0);
    hipLaunchKernelGGL(gmm_stats_fb, dim3(1024), dim3(256), 0, stream, mu, lab, ws, B);
  }
  hipLaunchKernelGGL(gmm_finalize, dim3(1), dim3(512), 0, stream, ws, out, B);
}

// Round 8
// 926.301 us; speedup vs baseline: 1.1709x; 1.1709x over previous
//
#include <hip/hip_runtime.h>
#include <math.h>

#define K 32
#define G 8
#define SIGMA_V 1.0f
#define RF __builtin_amdgcn_readfirstlane
#define RPB 512            // rows per stats block (4 waves x 128)
#define RPW 128            // rows per wave

// ws layout (4-byte units)
#define RAW_OFF   0        // float[G*K*K] = 8192
#define MUSUM_OFF 8192     // float[G*K]   = 256
#define CNT_OFF   8448     // float[G]
#define ICNT_OFF  8456     // int[G]
#define CUR_OFF   8464     // int[G]
#define DESC_OFF  8480     // int[3 * nblk] (nblk = B/RPB + G = 2056 -> 6168 ints < 7904)
#define IDX_OFF   16384    // int[B + 16*G]
#define HDR_INTS  16384

#define WAITV(n) asm volatile("s_waitcnt vmcnt(" #n ")" ::: "memory")
typedef __attribute__((address_space(3))) void lds_void;
typedef __attribute__((address_space(1))) void glb_void;
#define GLL(gsrc, ldst) __builtin_amdgcn_global_load_lds((const glb_void*)(gsrc), (lds_void*)(ldst), 16, 0, 0)

// ---------------- histogram ----------------
__global__ __launch_bounds__(256, 8) void gmm_hist(const int* __restrict__ lab,
                                                   int* __restrict__ wsI, int B) {
  __shared__ int h[G];
  if (threadIdx.x < G) h[threadIdx.x] = 0;
  __syncthreads();
  int c[G];
  #pragma unroll
  for (int g = 0; g < G; ++g) c[g] = 0;
  const int nt = gridDim.x * blockDim.x;
  const int4* lab4 = reinterpret_cast<const int4*>(lab);
  for (int i = blockIdx.x * blockDim.x + threadIdx.x; i < B / 4; i += nt) {
    const int4 v = lab4[i];
    #pragma unroll
    for (int g = 0; g < G; ++g)
      c[g] += (v.x == g) + (v.y == g) + (v.z == g) + (v.w == g);
  }
  const int lane = threadIdx.x & 63;
  #pragma unroll
  for (int g = 0; g < G; ++g) {
    int t = c[g];
    #pragma unroll
    for (int off = 32; off >= 1; off >>= 1) t += __shfl_xor(t, off);
    if (lane == 0) atomicAdd(&h[g], t);
  }
  __syncthreads();
  if (threadIdx.x < G) atomicAdd(&wsI[ICNT_OFF + threadIdx.x], h[threadIdx.x]);
}

// ---------------- prep: 16-padded offsets, cursors, per-block descriptors ----------------
__global__ void gmm_prep(float* __restrict__ ws, int* __restrict__ wsI, int B, int nblk) {
  __shared__ int off[G], bb[G + 1], scnt[G];
  const int tid = threadIdx.x;
  if (tid == 0) {
    int o = 0, b = 0;
    for (int g = 0; g < G; ++g) {
      const int c = wsI[ICNT_OFF + g];
      scnt[g] = c; off[g] = o; bb[g] = b;
      ws[CNT_OFF + g] = (float)c;
      wsI[CUR_OFF + g] = o;
      o = (o + c + 15) & ~15;          // 16-int padding: block starts stay 16-aligned
      b += (c + RPB - 1) / RPB;
    }
    bb[G] = b;
  }
  __syncthreads();
  for (int t = tid; t < nblk; t += blockDim.x) {
    int st = 0, cn = 0, gg = 0;
    #pragma unroll
    for (int g = 0; g < G; ++g) {
      if (t >= bb[g] && t < bb[g + 1]) {
        const int k = t - bb[g];
        st = off[g] + k * RPB;
        const int rem = scnt[g] - k * RPB;
        cn = rem < RPB ? rem : RPB;
        gg = g;
      }
    }
    wsI[DESC_OFF + 3 * t]     = st;
    wsI[DESC_OFF + 3 * t + 1] = cn;
    wsI[DESC_OFF + 3 * t + 2] = gg;
  }
}

// ---------------- scatter: build group-sorted row-index array ----------------
__global__ __launch_bounds__(256, 8) void gmm_scatter(const int* __restrict__ lab,
                                                      int* __restrict__ wsI, int B) {
  __shared__ int lcnt[G], lbase[G], lpos[G];
  const int tid = threadIdx.x;
  const int base = blockIdx.x * 1024;
  if (tid < G) { lcnt[tid] = 0; lpos[tid] = 0; }
  __syncthreads();
  const int4 v = *reinterpret_cast<const int4*>(lab + base + tid * 4);
  atomicAdd(&lcnt[v.x], 1); atomicAdd(&lcnt[v.y], 1);
  atomicAdd(&lcnt[v.z], 1); atomicAdd(&lcnt[v.w], 1);
  __syncthreads();
  if (tid < G) lbase[tid] = atomicAdd(&wsI[CUR_OFF + tid], lcnt[tid]);
  __syncthreads();
  int p;
  p = atomicAdd(&lpos[v.x], 1); wsI[IDX_OFF + lbase[v.x] + p] = base + tid * 4;
  p = atomicAdd(&lpos[v.y], 1); wsI[IDX_OFF + lbase[v.y] + p] = base + tid * 4 + 1;
  p = atomicAdd(&lpos[v.z], 1); wsI[IDX_OFF + lbase[v.z] + p] = base + tid * 4 + 2;
  p = atomicAdd(&lpos[v.w], 1); wsI[IDX_OFF + lbase[v.w] + p] = base + tid * 4 + 3;
}

// ---------------- stats: LDS-staged gather, per-wave double buffer, counted vmcnt ----------------
#define OUTER(a, b) { \
  acc[0]=fmaf(a.x,b.x,acc[0]);   acc[1]=fmaf(a.x,b.y,acc[1]);   acc[2]=fmaf(a.x,b.z,acc[2]);   acc[3]=fmaf(a.x,b.w,acc[3]); \
  acc[4]=fmaf(a.y,b.x,acc[4]);   acc[5]=fmaf(a.y,b.y,acc[5]);   acc[6]=fmaf(a.y,b.z,acc[6]);   acc[7]=fmaf(a.y,b.w,acc[7]); \
  acc[8]=fmaf(a.z,b.x,acc[8]);   acc[9]=fmaf(a.z,b.y,acc[9]);   acc[10]=fmaf(a.z,b.z,acc[10]); acc[11]=fmaf(a.z,b.w,acc[11]); \
  acc[12]=fmaf(a.w,b.x,acc[12]); acc[13]=fmaf(a.w,b.y,acc[13]); acc[14]=fmaf(a.w,b.z,acc[14]); acc[15]=fmaf(a.w,b.w,acc[15]); \
  if (i8 == 0) { ms[0]+=b.x; ms[1]+=b.y; ms[2]+=b.z; ms[3]+=b.w; } }

// stage 16 rows (2 x global_load_lds dwordx4): lane l writes bytes [l*16,l*16+16) of a
// linear [16][32]f tile -> row l>>3, floats (l&7)*4.. ; per-lane src = mu + idx*128 + (l&7)*16
#define STAGE(vlo, vhi, b) do { \
  float* db = &lds[wave * 1024 + (b) * 512]; \
  GLL(mu + (size_t)(unsigned)(vlo) * K + lf * 4, db); \
  GLL(mu + (size_t)(unsigned)(vhi) * K + lf * 4, db + 256); \
} while (0)

#define COMPUTE(b) do { \
  const float* sb = &lds[wave * 1024 + (b) * 512]; \
  _Pragma("unroll") \
  for (int r = 0; r < 16; ++r) { \
    const float4 a = *reinterpret_cast<const float4*>(&sb[r * 32 + i8 * 4]); \
    const float4 bv = *reinterpret_cast<const float4*>(&sb[r * 32 + j8 * 4]); \
    OUTER(a, bv); \
  } \
} while (0)

__global__ __launch_bounds__(256, 8) void gmm_stats3(const float* __restrict__ mu,
                                                     const int* __restrict__ wsI,
                                                     float* __restrict__ ws) {
  __shared__ float lds[4224];                // stage [4][2][16][32] (4096f) + red overlay (4224f)
  const int bd  = blockIdx.x * 3;
  const int s   = RF(wsI[DESC_OFF + bd]);
  const int cnt = RF(wsI[DESC_OFF + bd + 1]);
  const int g   = RF(wsI[DESC_OFF + bd + 2]);
  if (cnt <= 0) return;                      // uniform for whole block

  const int tid = threadIdx.x, wave = tid >> 6, lane = tid & 63;
  const int i8 = lane >> 3, j8 = lane & 7;   // 8x8 lane grid, 4x4 tile/lane
  const int lg = lane >> 3, lf = lane & 7;   // staging lane mapping
  float acc[16], ms[4];
  #pragma unroll
  for (int e = 0; e < 16; ++e) acc[e] = 0.f;
  ms[0] = ms[1] = ms[2] = ms[3] = 0.f;

  int wcnt = cnt - wave * RPW;
  wcnt = wcnt < 0 ? 0 : (wcnt > RPW ? RPW : wcnt);
  const int* idxp = wsI + IDX_OFF + s + wave * RPW;

  const int nch = wcnt >> 4;                 // full 16-row chunks (8 for interior blocks)
  int alo = 0, ahi = 0, slo = 0, shi = 0, tlo = 0, thi = 0;
  if (nch > 0) { alo = idxp[lg]; ahi = idxp[8 + lg]; }         // idx(0)
  if (nch > 1) { slo = idxp[16 + lg]; shi = idxp[24 + lg]; }   // idx(1)
  if (nch > 0) {
    if (nch > 1) WAITV(2); else WAITV(0);    // idx(0) ready; idx(1) may fly
    STAGE(alo, ahi, 0);
  }
  int buf = 0;
  for (int k = 0; k < nch; ++k) {
    const bool h1 = (k + 1) < nch, h2 = (k + 2) < nch;
    if (h2) { tlo = idxp[(k + 2) * 16 + lg]; thi = idxp[(k + 2) * 16 + 8 + lg]; }
    if (h1) {
      if (h2) { WAITV(4); } else { WAITV(2); }   // idx(k+1) ready
      STAGE(slo, shi, buf ^ 1);
      if (h2) { WAITV(4); } else { WAITV(2); }   // stage(k) landed
    } else {
      WAITV(0);                                  // last chunk: drain
    }
    COMPUTE(buf);
    slo = tlo; shi = thi;
    buf ^= 1;
  }
  for (int q = nch << 4; q < wcnt; ++q) {    // tail <= 15 rows: direct uniform loads
    const int r = idxp[q];
    const float* rp = mu + (size_t)(unsigned)r * K;
    const float4 a = *reinterpret_cast<const float4*>(rp + i8 * 4);
    const float4 bv = *reinterpret_cast<const float4*>(rp + j8 * 4);
    OUTER(a, bv);
  }

  // reduce overlay reuses stage LDS: barrier first (all waves done computing)
  __syncthreads();
  #pragma unroll
  for (int e = 0; e < 16; ++e) lds[wave * 1056 + e * 64 + lane] = acc[e];
  if (i8 == 0) {
    #pragma unroll
    for (int e = 0; e < 4; ++e) lds[wave * 1056 + 1024 + j8 * 4 + e] = ms[e];
  }
  __syncthreads();
  for (int t = tid; t < 1056; t += 256) {
    const float sm = lds[t] + lds[1056 + t] + lds[2112 + t] + lds[3168 + t];
    if (t < 1024) {
      const int e = t >> 6, ln = t & 63;
      const int row = 4 * (ln >> 3) + (e >> 2), col = 4 * (ln & 7) + (e & 3);
      atomicAdd(ws + RAW_OFF + g * K * K + row * K + col, sm);
    } else {
      atomicAdd(ws + MUSUM_OFF + g * K + (t - 1024), sm);
    }
  }
}

// ---------------- fallback stats (round-2 style) if ws too small ----------------
#define ACC_CASE(gc_, Av, Bv_) do{ \
  facc[gc_][0]=fmaf(Av.x,Bv_.x,facc[gc_][0]); facc[gc_][1]=fmaf(Av.x,Bv_.y,facc[gc_][1]); \
  facc[gc_][2]=fmaf(Av.y,Bv_.x,facc[gc_][2]); facc[gc_][3]=fmaf(Av.y,Bv_.y,facc[gc_][3]); \
  if (a_blk==0){ msum[gc_][0]+=Bv_.x; msum[gc_][1]+=Bv_.y; } }while(0)
#define PROC(gv, Av, Bv_) switch(gv){ \
  case 0: ACC_CASE(0,Av,Bv_); break; case 1: ACC_CASE(1,Av,Bv_); break; \
  case 2: ACC_CASE(2,Av,Bv_); break; case 3: ACC_CASE(3,Av,Bv_); break; \
  case 4: ACC_CASE(4,Av,Bv_); break; case 5: ACC_CASE(5,Av,Bv_); break; \
  case 6: ACC_CASE(6,Av,Bv_); break; default: ACC_CASE(7,Av,Bv_); break; }

__global__ __launch_bounds__(256, 4) void gmm_stats_fb(const float* __restrict__ mu,
                                                       const int* __restrict__ lab,
                                                       float* __restrict__ ws, int B) {
  const int tid = threadIdx.x;
  const int a_blk = tid >> 4, b_blk = tid & 15;
  const int rpb = B / 1024;
  const long rbase = (long)blockIdx.x * rpb;
  float facc[G][4]; float msum[G][2];
  #pragma unroll
  for (int g = 0; g < G; ++g) { facc[g][0]=facc[g][1]=facc[g][2]=facc[g][3]=0.f; msum[g][0]=msum[g][1]=0.f; }
  const float2* __restrict__ mu2 = reinterpret_cast<const float2*>(mu);
  for (int q = 0; q < rpb; ++q) {
    const long r = rbase + q;
    const float2 Av = mu2[r * 16 + a_blk];
    const float2 Bv_ = mu2[r * 16 + b_blk];
    const int g0 = RF(lab[r]);
    PROC(g0, Av, Bv_);
  }
  const int arow = a_blk * 2, bcol = b_blk * 2;
  #pragma unroll
  for (int g = 0; g < G; ++g) {
    float* base = &ws[RAW_OFF + g * K * K];
    atomicAdd(base + (arow)*K + bcol, facc[g][0]);
    atomicAdd(base + (arow)*K + bcol + 1, facc[g][1]);
    atomicAdd(base + (arow+1)*K + bcol, facc[g][2]);
    atomicAdd(base + (arow+1)*K + bcol + 1, facc[g][3]);
  }
  if (a_blk == 0)
    #pragma unroll
    for (int g = 0; g < G; ++g) {
      atomicAdd(&ws[MUSUM_OFF + g*K + bcol], msum[g][0]);
      atomicAdd(&ws[MUSUM_OFF + g*K + bcol + 1], msum[g][1]);
    }
}

// ---------------- finalize (fp64, validated rounds 2/5/6/7) ----------------
__global__ __launch_bounds__(512, 1) void gmm_finalize(const float* __restrict__ ws,
                                                       float* __restrict__ out, int B) {
  __shared__ double sig[G][K][K];
  __shared__ double inv[G][K][K];
  __shared__ double mg[G][K];
  __shared__ double ldet[G];
  __shared__ double cshared[G];
  __shared__ double pairsum[G];
  const int tid = threadIdx.x;
  const int w = tid >> 6;
  const int lane = tid & 63;

  if (tid < G) cshared[tid] = (double)ws[CNT_OFF + tid];
  __syncthreads();
  const double cinv = 1.0 / cshared[w];
  if (lane < K) mg[w][lane] = (double)ws[MUSUM_OFF + w * K + lane] * cinv;
  __syncthreads();
  for (int e = lane; e < K * K; e += 64) {
    const int a = e >> 5, b = e & 31;
    double s = (double)ws[RAW_OFF + w * K * K + e] * cinv - mg[w][a] * mg[w][b];
    if (a == b) s += (double)SIGMA_V;
    sig[w][a][b] = s;
  }
  __syncthreads();

  const int c = lane & 31;
  double col[K];
  #pragma unroll
  for (int i2 = 0; i2 < K; ++i2) {
    double sv = sig[w][i2][c];
    col[i2] = (lane < K) ? sv : ((i2 == c) ? 1.0 : 0.0);
  }
  double ld = 0.0;
  #pragma unroll
  for (int j2 = 0; j2 < K; ++j2) {
    double rowj = col[j2];
    double p = __shfl(rowj, j2);
    double pinv = 1.0 / p;
    ld += log(p);
    double scaled = rowj * pinv;
    #pragma unroll
    for (int i2 = 0; i2 < K; ++i2) {
      if (i2 == j2) continue;
      double bij = __shfl(col[i2], j2);
      col[i2] = fma(-bij, scaled, col[i2]);
    }
    col[j2] = scaled;
  }
  if (lane >= K) {
    #pragma unroll
    for (int i2 = 0; i2 < K; ++i2) inv[w][i2][lane - K] = col[i2];
  }
  if (lane == 0) ldet[w] = ld;
  __syncthreads();

  double accp = 0.0;
  for (int jj = 0; jj < G; ++jj) {
    const bool ok = (w < G - 1) && (jj >= 1) && (w != jj);
    if (ok) {
      double t = 0.0;
      for (int e = lane; e < K * K; e += 64) {
        const int a = e >> 5, b = e & 31;
        const double da = mg[jj][a] - mg[w][a];
        const double db = mg[jj][b] - mg[w][b];
        t += inv[jj][a][b] * (sig[w][a][b] + da * db);
      }
      #pragma unroll
      for (int off = 32; off >= 1; off >>= 1) t += __shfl_xor(t, off);
      if (lane == 0) accp += 0.5 * (t - (double)K + ldet[jj] - ldet[w]) * cshared[w] * cshared[jj];
    }
  }
  if (lane == 0) pairsum[w] = accp;
  __syncthreads();
  if (tid == 0) {
    double tot = 0.0;
    #pragma unroll
    for (int q = 0; q < G; ++q) tot += pairsum[q];
    const double Bf = (double)B;
    out[0] = (float)(tot / (Bf * Bf));
  }
}

extern "C" void kernel_launch(void* const* d_in, const int* in_sizes, int n_in,
                              void* d_out, int out_size, void* d_ws, size_t ws_size,
                              hipStream_t stream) {
  const float* mu = (const float*)d_in[0];
  const int* lab = (const int*)d_in[1];
  float* ws = (float*)d_ws;
  int* wsI = (int*)d_ws;
  float* out = (float*)d_out;
  const int B = in_sizes[1];

  hipMemsetAsync(d_ws, 0, (size_t)DESC_OFF * 4, stream);
  hipLaunchKernelGGL(gmm_hist, dim3(256), dim3(256), 0, stream, lab, wsI, B);

  const size_t need = (size_t)(HDR_INTS + B + 16 * G + 32) * 4;
  if (ws_size >= need) {
    const int nblk = (B + RPB - 1) / RPB + G;
    hipLaunchKernelGGL(gmm_prep, dim3(1), dim3(256), 0, stream, ws, wsI, B, nblk);
    hipLaunchKernelGGL(gmm_scatter, dim3(B / 1024), dim3(256), 0, stream, lab, wsI, B);
    hipLaunchKernelGGL(gmm_stats3, dim3(nblk), dim3(256), 0, stream, mu, wsI, ws);
  } else {
    hipLaunchKernelGGL(gmm_prep, dim3(1), dim3(256), 0, stream, ws, wsI, B, 0);
    hipLaunchKernelGGL(gmm_stats_fb, dim3(1024), dim3(256), 0, stream, mu, lab, ws, B);
  }
  hipLaunchKernelGGL(gmm_finalize, dim3(1), dim3(512), 0, stream, ws, out, B);
}

// Round 9
// 209.908 us; speedup vs baseline: 5.1670x; 4.4129x over previous
//
#include <hip/hip_runtime.h>
#include <math.h>

#define K 32
#define G 8
#define SIGMA_V 1.0f
#define RF __builtin_amdgcn_readfirstlane
#define RPB 512            // rows per stats block (4 waves x 128)
#define RPW 128            // rows per wave

// ws layout (4-byte units)
#define RAW_OFF   0        // float[G*K*K] = 8192
#define MUSUM_OFF 8192     // float[G*K]   = 256
#define CNT_OFF   8448     // float[G]
#define ICNT_OFF  8456     // int[G]
#define CUR_OFF   8464     // int[G]
#define DESC_OFF  8480     // int[3 * nblk] (nblk = B/RPB + G = 2056 -> 6168 ints < 7904)
#define IDX_OFF   16384    // int[B + 16*G]
#define HDR_INTS  16384

#define WAITV(n) asm volatile("s_waitcnt vmcnt(" #n ")" ::: "memory")
typedef __attribute__((address_space(3))) void lds_void;
typedef __attribute__((address_space(1))) void glb_void;
#define GLL(gsrc, ldst) __builtin_amdgcn_global_load_lds((const glb_void*)(gsrc), (lds_void*)(ldst), 16, 0, 0)

// ---------------- histogram ----------------
__global__ __launch_bounds__(256, 8) void gmm_hist(const int* __restrict__ lab,
                                                   int* __restrict__ wsI, int B) {
  __shared__ int h[G];
  if (threadIdx.x < G) h[threadIdx.x] = 0;
  __syncthreads();
  int c[G];
  #pragma unroll
  for (int g = 0; g < G; ++g) c[g] = 0;
  const int nt = gridDim.x * blockDim.x;
  const int4* lab4 = reinterpret_cast<const int4*>(lab);
  for (int i = blockIdx.x * blockDim.x + threadIdx.x; i < B / 4; i += nt) {
    const int4 v = lab4[i];
    #pragma unroll
    for (int g = 0; g < G; ++g)
      c[g] += (v.x == g) + (v.y == g) + (v.z == g) + (v.w == g);
  }
  const int lane = threadIdx.x & 63;
  #pragma unroll
  for (int g = 0; g < G; ++g) {
    int t = c[g];
    #pragma unroll
    for (int off = 32; off >= 1; off >>= 1) t += __shfl_xor(t, off);
    if (lane == 0) atomicAdd(&h[g], t);
  }
  __syncthreads();
  if (threadIdx.x < G) atomicAdd(&wsI[ICNT_OFF + threadIdx.x], h[threadIdx.x]);
}

// ---------------- prep: 16-padded offsets, cursors, per-block descriptors ----------------
__global__ void gmm_prep(float* __restrict__ ws, int* __restrict__ wsI, int B, int nblk) {
  __shared__ int off[G], bb[G + 1], scnt[G];
  const int tid = threadIdx.x;
  if (tid == 0) {
    int o = 0, b = 0;
    for (int g = 0; g < G; ++g) {
      const int c = wsI[ICNT_OFF + g];
      scnt[g] = c; off[g] = o; bb[g] = b;
      ws[CNT_OFF + g] = (float)c;
      wsI[CUR_OFF + g] = o;
      o = (o + c + 15) & ~15;          // 16-int padding: block starts stay 16-aligned
      b += (c + RPB - 1) / RPB;
    }
    bb[G] = b;
  }
  __syncthreads();
  for (int t = tid; t < nblk; t += blockDim.x) {
    int st = 0, cn = 0, gg = 0;
    #pragma unroll
    for (int g = 0; g < G; ++g) {
      if (t >= bb[g] && t < bb[g + 1]) {
        const int k = t - bb[g];
        st = off[g] + k * RPB;
        const int rem = scnt[g] - k * RPB;
        cn = rem < RPB ? rem : RPB;
        gg = g;
      }
    }
    wsI[DESC_OFF + 3 * t]     = st;
    wsI[DESC_OFF + 3 * t + 1] = cn;
    wsI[DESC_OFF + 3 * t + 2] = gg;
  }
}

// ---------------- scatter: build group-sorted row-index array ----------------
__global__ __launch_bounds__(256, 8) void gmm_scatter(const int* __restrict__ lab,
                                                      int* __restrict__ wsI, int B) {
  __shared__ int lcnt[G], lbase[G], lpos[G];
  const int tid = threadIdx.x;
  const int base = blockIdx.x * 1024;
  if (tid < G) { lcnt[tid] = 0; lpos[tid] = 0; }
  __syncthreads();
  const int4 v = *reinterpret_cast<const int4*>(lab + base + tid * 4);
  atomicAdd(&lcnt[v.x], 1); atomicAdd(&lcnt[v.y], 1);
  atomicAdd(&lcnt[v.z], 1); atomicAdd(&lcnt[v.w], 1);
  __syncthreads();
  if (tid < G) lbase[tid] = atomicAdd(&wsI[CUR_OFF + tid], lcnt[tid]);
  __syncthreads();
  int p;
  p = atomicAdd(&lpos[v.x], 1); wsI[IDX_OFF + lbase[v.x] + p] = base + tid * 4;
  p = atomicAdd(&lpos[v.y], 1); wsI[IDX_OFF + lbase[v.y] + p] = base + tid * 4 + 1;
  p = atomicAdd(&lpos[v.z], 1); wsI[IDX_OFF + lbase[v.z] + p] = base + tid * 4 + 2;
  p = atomicAdd(&lpos[v.w], 1); wsI[IDX_OFF + lbase[v.w] + p] = base + tid * 4 + 3;
}

// ---------------- stats: LDS-staged gather, per-wave double buffer, counted vmcnt ----------------
#define OUTER(a, b) { \
  acc[0]=fmaf(a.x,b.x,acc[0]);   acc[1]=fmaf(a.x,b.y,acc[1]);   acc[2]=fmaf(a.x,b.z,acc[2]);   acc[3]=fmaf(a.x,b.w,acc[3]); \
  acc[4]=fmaf(a.y,b.x,acc[4]);   acc[5]=fmaf(a.y,b.y,acc[5]);   acc[6]=fmaf(a.y,b.z,acc[6]);   acc[7]=fmaf(a.y,b.w,acc[7]); \
  acc[8]=fmaf(a.z,b.x,acc[8]);   acc[9]=fmaf(a.z,b.y,acc[9]);   acc[10]=fmaf(a.z,b.z,acc[10]); acc[11]=fmaf(a.z,b.w,acc[11]); \
  acc[12]=fmaf(a.w,b.x,acc[12]); acc[13]=fmaf(a.w,b.y,acc[13]); acc[14]=fmaf(a.w,b.z,acc[14]); acc[15]=fmaf(a.w,b.w,acc[15]); \
  if (i8 == 0) { ms[0]+=b.x; ms[1]+=b.y; ms[2]+=b.z; ms[3]+=b.w; } }

// stage 16 rows (2 x global_load_lds dwordx4): lane l writes bytes [l*16,l*16+16) of a
// linear [16][32]f tile -> row l>>3, floats (l&7)*4.. ; per-lane src = mu + idx*128 + (l&7)*16
#define STAGE(vlo, vhi, b) do { \
  float* db = &lds[wave * 1024 + (b) * 512]; \
  GLL(mu + (size_t)(unsigned)(vlo) * K + lf * 4, db); \
  GLL(mu + (size_t)(unsigned)(vhi) * K + lf * 4, db + 256); \
} while (0)

#define COMPUTE(b) do { \
  const float* sb = &lds[wave * 1024 + (b) * 512]; \
  _Pragma("unroll") \
  for (int r = 0; r < 16; ++r) { \
    const float4 a = *reinterpret_cast<const float4*>(&sb[r * 32 + i8 * 4]); \
    const float4 bv = *reinterpret_cast<const float4*>(&sb[r * 32 + j8 * 4]); \
    OUTER(a, bv); \
  } \
} while (0)

// (256,4): 128-VGPR budget. R7/R8 lesson: any 64-reg cap makes LLVM spill the
// long-lived acc[16] -> GBs of scratch RMW. Demand here is ~50 regs; if the
// allocator lands <=64, HW can still co-resident 8 waves/SIMD.
__global__ __launch_bounds__(256, 4) void gmm_stats3(const float* __restrict__ mu,
                                                     const int* __restrict__ wsI,
                                                     float* __restrict__ ws) {
  __shared__ float lds[4224];                // stage [4][2][16][32] (4096f) + red overlay (4224f)
  const int bd  = blockIdx.x * 3;
  const int s   = RF(wsI[DESC_OFF + bd]);
  const int cnt = RF(wsI[DESC_OFF + bd + 1]);
  const int g   = RF(wsI[DESC_OFF + bd + 2]);
  if (cnt <= 0) return;                      // uniform for whole block

  const int tid = threadIdx.x, wave = tid >> 6, lane = tid & 63;
  const int i8 = lane >> 3, j8 = lane & 7;   // 8x8 lane grid, 4x4 tile/lane
  const int lg = lane >> 3, lf = lane & 7;   // staging lane mapping
  float acc[16], ms[4];
  #pragma unroll
  for (int e = 0; e < 16; ++e) acc[e] = 0.f;
  ms[0] = ms[1] = ms[2] = ms[3] = 0.f;

  int wcnt = cnt - wave * RPW;
  wcnt = wcnt < 0 ? 0 : (wcnt > RPW ? RPW : wcnt);
  const int* idxp = wsI + IDX_OFF + s + wave * RPW;

  const int nch = wcnt >> 4;                 // full 16-row chunks (8 for interior blocks)
  int alo = 0, ahi = 0, slo = 0, shi = 0, tlo = 0, thi = 0;
  if (nch > 0) { alo = idxp[lg]; ahi = idxp[8 + lg]; }         // idx(0)
  if (nch > 1) { slo = idxp[16 + lg]; shi = idxp[24 + lg]; }   // idx(1)
  if (nch > 0) {
    if (nch > 1) WAITV(2); else WAITV(0);    // idx(0) ready; idx(1) may fly
    STAGE(alo, ahi, 0);
  }
  int buf = 0;
  for (int k = 0; k < nch; ++k) {
    const bool h1 = (k + 1) < nch, h2 = (k + 2) < nch;
    if (h2) { tlo = idxp[(k + 2) * 16 + lg]; thi = idxp[(k + 2) * 16 + 8 + lg]; }
    if (h1) {
      if (h2) { WAITV(4); } else { WAITV(2); }   // idx(k+1) ready
      STAGE(slo, shi, buf ^ 1);
      if (h2) { WAITV(4); } else { WAITV(2); }   // stage(k) landed
    } else {
      WAITV(0);                                  // last chunk: drain
    }
    COMPUTE(buf);
    slo = tlo; shi = thi;
    buf ^= 1;
  }
  for (int q = nch << 4; q < wcnt; ++q) {    // tail <= 15 rows: direct uniform loads
    const int r = idxp[q];
    const float* rp = mu + (size_t)(unsigned)r * K;
    const float4 a = *reinterpret_cast<const float4*>(rp + i8 * 4);
    const float4 bv = *reinterpret_cast<const float4*>(rp + j8 * 4);
    OUTER(a, bv);
  }

  // reduce overlay reuses stage LDS: barrier first (all waves done computing)
  __syncthreads();
  #pragma unroll
  for (int e = 0; e < 16; ++e) lds[wave * 1056 + e * 64 + lane] = acc[e];
  if (i8 == 0) {
    #pragma unroll
    for (int e = 0; e < 4; ++e) lds[wave * 1056 + 1024 + j8 * 4 + e] = ms[e];
  }
  __syncthreads();
  for (int t = tid; t < 1056; t += 256) {
    const float sm = lds[t] + lds[1056 + t] + lds[2112 + t] + lds[3168 + t];
    if (t < 1024) {
      const int e = t >> 6, ln = t & 63;
      const int row = 4 * (ln >> 3) + (e >> 2), col = 4 * (ln & 7) + (e & 3);
      atomicAdd(ws + RAW_OFF + g * K * K + row * K + col, sm);
    } else {
      atomicAdd(ws + MUSUM_OFF + g * K + (t - 1024), sm);
    }
  }
}

// ---------------- fallback stats (round-2 style) if ws too small ----------------
#define ACC_CASE(gc_, Av, Bv_) do{ \
  facc[gc_][0]=fmaf(Av.x,Bv_.x,facc[gc_][0]); facc[gc_][1]=fmaf(Av.x,Bv_.y,facc[gc_][1]); \
  facc[gc_][2]=fmaf(Av.y,Bv_.x,facc[gc_][2]); facc[gc_][3]=fmaf(Av.y,Bv_.y,facc[gc_][3]); \
  if (a_blk==0){ msum[gc_][0]+=Bv_.x; msum[gc_][1]+=Bv_.y; } }while(0)
#define PROC(gv, Av, Bv_) switch(gv){ \
  case 0: ACC_CASE(0,Av,Bv_); break; case 1: ACC_CASE(1,Av,Bv_); break; \
  case 2: ACC_CASE(2,Av,Bv_); break; case 3: ACC_CASE(3,Av,Bv_); break; \
  case 4: ACC_CASE(4,Av,Bv_); break; case 5: ACC_CASE(5,Av,Bv_); break; \
  case 6: ACC_CASE(6,Av,Bv_); break; default: ACC_CASE(7,Av,Bv_); break; }

__global__ __launch_bounds__(256, 4) void gmm_stats_fb(const float* __restrict__ mu,
                                                       const int* __restrict__ lab,
                                                       float* __restrict__ ws, int B) {
  const int tid = threadIdx.x;
  const int a_blk = tid >> 4, b_blk = tid & 15;
  const int rpb = B / 1024;
  const long rbase = (long)blockIdx.x * rpb;
  float facc[G][4]; float msum[G][2];
  #pragma unroll
  for (int g = 0; g < G; ++g) { facc[g][0]=facc[g][1]=facc[g][2]=facc[g][3]=0.f; msum[g][0]=msum[g][1]=0.f; }
  const float2* __restrict__ mu2 = reinterpret_cast<const float2*>(mu);
  for (int q = 0; q < rpb; ++q) {
    const long r = rbase + q;
    const float2 Av = mu2[r * 16 + a_blk];
    const float2 Bv_ = mu2[r * 16 + b_blk];
    const int g0 = RF(lab[r]);
    PROC(g0, Av, Bv_);
  }
  const int arow = a_blk * 2, bcol = b_blk * 2;
  #pragma unroll
  for (int g = 0; g < G; ++g) {
    float* base = &ws[RAW_OFF + g * K * K];
    atomicAdd(base + (arow)*K + bcol, facc[g][0]);
    atomicAdd(base + (arow)*K + bcol + 1, facc[g][1]);
    atomicAdd(base + (arow+1)*K + bcol, facc[g][2]);
    atomicAdd(base + (arow+1)*K + bcol + 1, facc[g][3]);
  }
  if (a_blk == 0)
    #pragma unroll
    for (int g = 0; g < G; ++g) {
      atomicAdd(&ws[MUSUM_OFF + g*K + bcol], msum[g][0]);
      atomicAdd(&ws[MUSUM_OFF + g*K + bcol + 1], msum[g][1]);
    }
}

// ---------------- finalize (fp64, validated rounds 2/5/6/7/8) ----------------
__global__ __launch_bounds__(512, 1) void gmm_finalize(const float* __restrict__ ws,
                                                       float* __restrict__ out, int B) {
  __shared__ double sig[G][K][K];
  __shared__ double inv[G][K][K];
  __shared__ double mg[G][K];
  __shared__ double ldet[G];
  __shared__ double cshared[G];
  __shared__ double pairsum[G];
  const int tid = threadIdx.x;
  const int w = tid >> 6;
  const int lane = tid & 63;

  if (tid < G) cshared[tid] = (double)ws[CNT_OFF + tid];
  __syncthreads();
  const double cinv = 1.0 / cshared[w];
  if (lane < K) mg[w][lane] = (double)ws[MUSUM_OFF + w * K + lane] * cinv;
  __syncthreads();
  for (int e = lane; e < K * K; e += 64) {
    const int a = e >> 5, b = e & 31;
    double s = (double)ws[RAW_OFF + w * K * K + e] * cinv - mg[w][a] * mg[w][b];
    if (a == b) s += (double)SIGMA_V;
    sig[w][a][b] = s;
  }
  __syncthreads();

  const int c = lane & 31;
  double col[K];
  #pragma unroll
  for (int i2 = 0; i2 < K; ++i2) {
    double sv = sig[w][i2][c];
    col[i2] = (lane < K) ? sv : ((i2 == c) ? 1.0 : 0.0);
  }
  double ld = 0.0;
  #pragma unroll
  for (int j2 = 0; j2 < K; ++j2) {
    double rowj = col[j2];
    double p = __shfl(rowj, j2);
    double pinv = 1.0 / p;
    ld += log(p);
    double scaled = rowj * pinv;
    #pragma unroll
    for (int i2 = 0; i2 < K; ++i2) {
      if (i2 == j2) continue;
      double bij = __shfl(col[i2], j2);
      col[i2] = fma(-bij, scaled, col[i2]);
    }
    col[j2] = scaled;
  }
  if (lane >= K) {
    #pragma unroll
    for (int i2 = 0; i2 < K; ++i2) inv[w][i2][lane - K] = col[i2];
  }
  if (lane == 0) ldet[w] = ld;
  __syncthreads();

  double accp = 0.0;
  for (int jj = 0; jj < G; ++jj) {
    const bool ok = (w < G - 1) && (jj >= 1) && (w != jj);
    if (ok) {
      double t = 0.0;
      for (int e = lane; e < K * K; e += 64) {
        const int a = e >> 5, b = e & 31;
        const double da = mg[jj][a] - mg[w][a];
        const double db = mg[jj][b] - mg[w][b];
        t += inv[jj][a][b] * (sig[w][a][b] + da * db);
      }
      #pragma unroll
      for (int off = 32; off >= 1; off >>= 1) t += __shfl_xor(t, off);
      if (lane == 0) accp += 0.5 * (t - (double)K + ldet[jj] - ldet[w]) * cshared[w] * cshared[jj];
    }
  }
  if (lane == 0) pairsum[w] = accp;
  __syncthreads();
  if (tid == 0) {
    double tot = 0.0;
    #pragma unroll
    for (int q = 0; q < G; ++q) tot += pairsum[q];
    const double Bf = (double)B;
    out[0] = (float)(tot / (Bf * Bf));
  }
}

extern "C" void kernel_launch(void* const* d_in, const int* in_sizes, int n_in,
                              void* d_out, int out_size, void* d_ws, size_t ws_size,
                              hipStream_t stream) {
  const float* mu = (const float*)d_in[0];
  const int* lab = (const int*)d_in[1];
  float* ws = (float*)d_ws;
  int* wsI = (int*)d_ws;
  float* out = (float*)d_out;
  const int B = in_sizes[1];

  hipMemsetAsync(d_ws, 0, (size_t)DESC_OFF * 4, stream);
  hipLaunchKernelGGL(gmm_hist, dim3(256), dim3(256), 0, stream, lab, wsI, B);

  const size_t need = (size_t)(HDR_INTS + B + 16 * G + 32) * 4;
  if (ws_size >= need) {
    const int nblk = (B + RPB - 1) / RPB + G;
    hipLaunchKernelGGL(gmm_prep, dim3(1), dim3(256), 0, stream, ws, wsI, B, nblk);
    hipLaunchKernelGGL(gmm_scatter, dim3(B / 1024), dim3(256), 0, stream, lab, wsI, B);
    hipLaunchKernelGGL(gmm_stats3, dim3(nblk), dim3(256), 0, stream, mu, wsI, ws);
  } else {
    hipLaunchKernelGGL(gmm_prep, dim3(1), dim3(256), 0, stream, ws, wsI, B, 0);
    hipLaunchKernelGGL(gmm_stats_fb, dim3(1024), dim3(256), 0, stream, mu, lab, ws, B);
  }
  hipLaunchKernelGGL(gmm_finalize, dim3(1), dim3(512), 0, stream, ws, out, B);
}